// Round 8
// baseline (195.480 us; speedup 1.0000x reference)
//
#include <hip/hip_runtime.h>
#include <hip/hip_bf16.h>

#define PP     512
#define KK     64
#define BB     32
#define LLEN   2048
#define NPOS   (BB * LLEN)   // 65536

typedef __attribute__((ext_vector_type(8)))  short short8;
typedef __attribute__((ext_vector_type(16))) float float16;

__device__ inline unsigned int pack_bf2(float lo, float hi) {
    __hip_bfloat162 h = __float22bfloat162_rn(make_float2(lo, hi));
    unsigned int u;
    __builtin_memcpy(&u, &h, 4);
    return u;   // low 16 = lo, high 16 = hi
}
__device__ inline float bf_lo(unsigned int v) { return __uint_as_float(v << 16); }
__device__ inline float bf_hi(unsigned int v) { return __uint_as_float(v & 0xffff0000u); }

// ---------------------------------------------------------------------------
// K1: unified B-operand fragments, 128 cols: n<64 -> l_hat[n], n>=64 -> f2w[n-64].
// Bu4[f*128 + n] = 8 bf16 of src[n][8f..8f+7] (f = 0..63).
// ---------------------------------------------------------------------------
__global__ void k1_prep(const float* __restrict__ C, const float* __restrict__ f2w,
                        ushort* __restrict__ Bu) {
    const int n = blockIdx.x;            // 0..127
    const float* src = (n < 64) ? (C + n * PP) : (f2w + (n - 64) * PP);
    const int t = threadIdx.x;
    float v0 = src[t];
    float v1 = src[t + 256];
    __shared__ float red[256];
    red[t] = v0 * v0 + v1 * v1;
    __syncthreads();
    for (int s = 128; s > 0; s >>= 1) {
        if (t < s) red[t] += red[t + s];
        __syncthreads();
    }
    const float inv = (n < 64) ? rsqrtf(red[0]) : 1.f;
    Bu[(((t >> 3)       * 128 + n) << 3) + (t & 7)] = (ushort)(pack_bf2(v0 * inv, 0.f) & 0xffffu);
    Bu[((((t + 256) >> 3)) * 128 + n) * 8 + (t & 7)] = (ushort)(pack_bf2(v1 * inv, 0.f) & 0xffffu);
}

// ---------------------------------------------------------------------------
// K2: producer/consumer MFMA GEMM.
// Block = 256 thr: waves 0,1 = consumers (wv0 -> cos cols 0-63, wv1 -> E2 cols
// 64-127); waves 2,3 = producers (gather + normalize + bf16-pack V rows).
// 32-position tiles, 4 tiles/block, ping-pong 2x32KB LDS -> 2 blocks/CU.
// A in LDS is PRE-NORMALIZED (e-hat); raw-emb norm exported to vnorm[pos].
// ---------------------------------------------------------------------------
__launch_bounds__(256)
__global__ void k2_gemm(const int* __restrict__ x, const float* __restrict__ V,
                        const uint4* __restrict__ Bu4,
                        unsigned int* __restrict__ Gt2, unsigned int* __restrict__ E2p,
                        float* __restrict__ vnorm) {
    __shared__ uint4 sA[2][32 * 64];   // 2 x 32 KB, row stride 64 frags, xor-swizzled

    const int tid  = threadIdx.x;
    const int lane = tid & 63;
    const int wv   = tid >> 6;
    const bool producer = (wv >= 2);
    const int tile0 = blockIdx.x * 4;

    // producer indexing: 128 threads, 4 per row, 32 rows
    const int pidx = tid & 127;
    const int pr   = pidx >> 2;        // row 0..31
    const int pq   = pidx & 3;         // quarter-interleave

    // ---- prologue: stage tile 0 into buf 0 ----
    if (producer) {
        const int tok = x[tile0 * 32 + pr];
        const float* src = V + (size_t)tok * PP + pq * 4;
        float4 pa[16], pb[16];
#pragma unroll
        for (int g = 0; g < 16; ++g) pa[g] = ((const float4*)src)[g * 4];
#pragma unroll
        for (int g = 0; g < 16; ++g) pb[g] = ((const float4*)src)[(g + 16) * 4];
        float nrm = 0.f;
#pragma unroll
        for (int g = 0; g < 16; ++g) {
            const float4 a = pa[g], b = pb[g];
            nrm = fmaf(a.x, a.x, fmaf(a.y, a.y, fmaf(a.z, a.z, fmaf(a.w, a.w, nrm))));
            nrm = fmaf(b.x, b.x, fmaf(b.y, b.y, fmaf(b.z, b.z, fmaf(b.w, b.w, nrm))));
        }
        nrm += __shfl_xor(nrm, 1, 64);
        nrm += __shfl_xor(nrm, 2, 64);
        const float inv = rsqrtf(nrm);
        if (pq == 0) vnorm[tile0 * 32 + pr] = sqrtf(nrm);
        const int swz = pr & 7;
#pragma unroll
        for (int g = 0; g < 16; ++g) {
            const float4 a = pa[g];
            uint2 w2; w2.x = pack_bf2(a.x * inv, a.y * inv); w2.y = pack_bf2(a.z * inv, a.w * inv);
            ((uint2*)&sA[0][pr * 64 + ((2 * g + (pq >> 1)) ^ swz)])[pq & 1] = w2;
        }
#pragma unroll
        for (int g = 0; g < 16; ++g) {
            const float4 a = pb[g];
            uint2 w2; w2.x = pack_bf2(a.x * inv, a.y * inv); w2.y = pack_bf2(a.z * inv, a.w * inv);
            ((uint2*)&sA[0][pr * 64 + ((2 * (g + 16) + (pq >> 1)) ^ swz)])[pq & 1] = w2;
        }
    }
    __syncthreads();

    const int l31 = lane & 31;
    const int cc  = lane >> 5;
    const int nh  = (wv & 1) * 64;         // consumer col-half
    const int abase = l31 * 64;
    const int aswz  = l31 & 7;

    for (int t = 0; t < 4; ++t) {
        const int buf = t & 1;
        if (!producer) {
            // ---- MFMA: 32 k-steps of 16 over sA[buf]; B from global (L1-hot) ----
            float16 acc0, acc1;
#pragma unroll
            for (int i = 0; i < 16; ++i) { acc0[i] = 0.f; acc1[i] = 0.f; }
#pragma unroll 8
            for (int ks = 0; ks < 32; ++ks) {
                const int ff = ks * 2 + cc;
                const uint4 av = sA[buf][abase + (ff ^ aswz)];
                const uint4 b0 = Bu4[ff * 128 + nh + l31];
                const uint4 b1 = Bu4[ff * 128 + nh + 32 + l31];
                short8 a8, t0, t1;
                __builtin_memcpy(&a8, &av, 16);
                __builtin_memcpy(&t0, &b0, 16);
                __builtin_memcpy(&t1, &b1, 16);
                acc0 = __builtin_amdgcn_mfma_f32_32x32x16_bf16(a8, t0, acc0, 0, 0, 0);
                acc1 = __builtin_amdgcn_mfma_f32_32x32x16_bf16(a8, t1, acc1, 0, 0, 0);
            }
            // ---- store tile outputs (A pre-normalized -> no rescale) ----
            const size_t posBase = (size_t)(tile0 + t) * 32;
            unsigned int* dst = (wv == 0) ? Gt2 : E2p;
#pragma unroll
            for (int reg = 0; reg < 16; ++reg) {
                const int rr = (reg & 3) + 8 * (reg >> 2) + 4 * cc;
                dst[(posBase + rr) * 32 + l31] = pack_bf2(acc0[reg], acc1[reg]);
            }
        } else if (t < 3) {
            // ---- stage tile t+1 into sA[buf^1] ----
            const int tile = tile0 + t + 1;
            const int tok = x[tile * 32 + pr];
            const float* src = V + (size_t)tok * PP + pq * 4;
            float4 pa[16], pb[16];
#pragma unroll
            for (int g = 0; g < 16; ++g) pa[g] = ((const float4*)src)[g * 4];
#pragma unroll
            for (int g = 0; g < 16; ++g) pb[g] = ((const float4*)src)[(g + 16) * 4];
            float nrm = 0.f;
#pragma unroll
            for (int g = 0; g < 16; ++g) {
                const float4 a = pa[g], b = pb[g];
                nrm = fmaf(a.x, a.x, fmaf(a.y, a.y, fmaf(a.z, a.z, fmaf(a.w, a.w, nrm))));
                nrm = fmaf(b.x, b.x, fmaf(b.y, b.y, fmaf(b.z, b.z, fmaf(b.w, b.w, nrm))));
            }
            nrm += __shfl_xor(nrm, 1, 64);
            nrm += __shfl_xor(nrm, 2, 64);
            const float inv = rsqrtf(nrm);
            if (pq == 0) vnorm[tile * 32 + pr] = sqrtf(nrm);
            const int swz = pr & 7;
            const int bb = buf ^ 1;
#pragma unroll
            for (int g = 0; g < 16; ++g) {
                const float4 a = pa[g];
                uint2 w2; w2.x = pack_bf2(a.x * inv, a.y * inv); w2.y = pack_bf2(a.z * inv, a.w * inv);
                ((uint2*)&sA[bb][pr * 64 + ((2 * g + (pq >> 1)) ^ swz)])[pq & 1] = w2;
            }
#pragma unroll
            for (int g = 0; g < 16; ++g) {
                const float4 a = pb[g];
                uint2 w2; w2.x = pack_bf2(a.x * inv, a.y * inv); w2.y = pack_bf2(a.z * inv, a.w * inv);
                ((uint2*)&sA[bb][pr * 64 + ((2 * (g + 16) + (pq >> 1)) ^ swz)])[pq & 1] = w2;
            }
        }
        __syncthreads();
    }
}

// ---------------------------------------------------------------------------
// K3: fused conv-max + online-softmax partial pooling. Block = (b, 64-l tile),
// 1024 blocks. Pooling weight folds vnorm (E2p holds normalized-emb dot f2w).
// pool[blk][0..63]=P_c, [64]=mx_c, [65]=se_c (stride 68)
// ---------------------------------------------------------------------------
__global__ void k3_convpool(const unsigned int* __restrict__ Gt2,
                            const unsigned int* __restrict__ E2p,
                            const float* __restrict__ vnorm,
                            const float* __restrict__ f1w, const float* __restrict__ f1b,
                            float* __restrict__ pool) {
    __shared__ unsigned int sT[74 * 33];   // 9.5 KB
    __shared__ float smv[64];
    __shared__ float sp[64];
    __shared__ float sscal[2];
    __shared__ float sred[8][64];

    const int b  = blockIdx.x >> 5;
    const int l0 = (blockIdx.x & 31) * 64;
    const int t  = threadIdx.x;

    for (int idx = t; idx < 74 * 32; idx += 256) {
        const int row = idx >> 5, col = idx & 31;
        const int gl = l0 - 5 + row;
        sT[row * 33 + col] = (gl >= 0 && gl < LLEN)
            ? Gt2[((size_t)b * LLEN + gl) * 32 + col] : 0u;
    }
    __syncthreads();

    float w[11];
#pragma unroll
    for (int j = 0; j < 11; ++j) w[j] = f1w[j];
    const int j = t & 31;
    const int h = t >> 5;                  // 0..7
    const float bias0 = f1b[j], bias1 = f1b[j + 32];
#pragma unroll
    for (int i = 0; i < 8; ++i) {
        const int lr = i * 8 + h;          // 0..63
        float u0 = 0.f, u1 = 0.f;
#pragma unroll
        for (int tap = 0; tap < 11; ++tap) {
            const unsigned int v = sT[(lr + tap) * 33 + j];
            u0 = fmaf(bf_lo(v), w[tap], u0);
            u1 = fmaf(bf_hi(v), w[tap], u1);
        }
        float m = fmaxf(fmaxf(u0 + bias0, 0.f), fmaxf(u1 + bias1, 0.f));
#pragma unroll
        for (int off = 16; off > 0; off >>= 1)
            m = fmaxf(m, __shfl_xor(m, off, 64));
        if (j == 0) smv[lr] = m;
    }
    __syncthreads();

    if (t < 64) {
        float v = smv[t];
#pragma unroll
        for (int off = 32; off > 0; off >>= 1)
            v = fmaxf(v, __shfl_xor(v, off, 64));
        if (t == 0) sscal[0] = v;
    }
    __syncthreads();
    const float mx = sscal[0];
    if (t < 64) sp[t] = __expf(smv[t] - mx);
    __syncthreads();
    if (t < 64) {
        float s = sp[t];
#pragma unroll
        for (int off = 32; off > 0; off >>= 1)
            s += __shfl_xor(s, off, 64);
        if (t == 0) sscal[1] = s;
    }

    // partial pooling: weight = softmax-numerator * ||emb|| (E2p is normalized)
    float a0 = 0.f, a1 = 0.f;
#pragma unroll
    for (int i = 0; i < 8; ++i) {
        const int l = i * 8 + h;
        const float wgt = sp[l] * vnorm[b * LLEN + l0 + l];
        const unsigned int e = E2p[((size_t)b * LLEN + l0 + l) * 32 + j];
        a0 = fmaf(wgt, bf_lo(e), a0);
        a1 = fmaf(wgt, bf_hi(e), a1);
    }
    sred[h][j]      = a0;
    sred[h][j + 32] = a1;
    __syncthreads();
    if (t < 64) {
        float r = 0.f;
#pragma unroll
        for (int hh = 0; hh < 8; ++hh) r += sred[hh][t];
        float* dst = pool + (size_t)blockIdx.x * 68;
        dst[t] = r;
        if (t == 0) { dst[64] = sscal[0]; dst[65] = sscal[1]; }
    }
}

// ---------------------------------------------------------------------------
// K6: combine 32 chunk-partials per b with online-softmax rescale + head bias.
// ---------------------------------------------------------------------------
__global__ void k6_final(const float* __restrict__ pool, const float* __restrict__ f2b,
                         float* __restrict__ out) {
    const int b = blockIdx.x;
    const int k = threadIdx.x;   // 64 threads
    float M = -1e30f;
#pragma unroll
    for (int c = 0; c < 32; ++c)
        M = fmaxf(M, pool[(size_t)(b * 32 + c) * 68 + 64]);
    float tot = 0.f, num = 0.f;
#pragma unroll
    for (int c = 0; c < 32; ++c) {
        const float* pc = pool + (size_t)(b * 32 + c) * 68;
        const float sc = __expf(pc[64] - M);
        tot = fmaf(sc, pc[65], tot);
        num = fmaf(sc, pc[k], num);
    }
    out[b * KK + k] = (num / tot) * (1.f / 2048.f) + f2b[k];
}

extern "C" void kernel_launch(void* const* d_in, const int* in_sizes, int n_in,
                              void* d_out, int out_size, void* d_ws, size_t ws_size,
                              hipStream_t stream) {
    const int*   x   = (const int*)d_in[0];
    const float* V   = (const float*)d_in[1];
    const float* C   = (const float*)d_in[2];
    const float* f1w = (const float*)d_in[3];
    const float* f1b = (const float*)d_in[4];
    const float* f2w = (const float*)d_in[5];
    const float* f2b = (const float*)d_in[6];
    float* out = (float*)d_out;

    float* ws = (float*)d_ws;
    ushort* Bu = (ushort*)ws;                             // 65536 ushort (32768 floats)
    unsigned int* Gt2 = (unsigned int*)(ws + 32768);      // NPOS*32 uints
    unsigned int* E2p = Gt2 + (size_t)NPOS * 32;          // NPOS*32 uints
    float* pool  = (float*)(E2p + (size_t)NPOS * 32);     // 1024*68 floats
    float* vnorm = pool + 1024 * 68;                      // NPOS floats

    k1_prep    <<<128, 256, 0, stream>>>(C, f2w, Bu);
    k2_gemm    <<<NPOS / 128, 256, 0, stream>>>(x, V, (const uint4*)Bu, Gt2, E2p, vnorm);
    k3_convpool<<<BB * 32, 256, 0, stream>>>(Gt2, E2p, vnorm, f1w, f1b, pool);
    k6_final   <<<BB, 64, 0, stream>>>(pool, f2b, out);
}